// Round 1
// baseline (374.403 us; speedup 1.0000x reference)
//
#include <hip/hip_runtime.h>

// Problem: preds (N=8,S=6,C=4,H=512,W=512) fp32, targets (8,6,512,512) int32.
// out = (1/N) * sum [logsumexp_c(preds) - preds[target]]   (scalar)
//
// R1: 12288 same-address atomicAdds serialized (168 us flat).
// R2: two-stage reduction -> 310 us (harness fixed overhead ~210 us).
// R3: batched loads @1024 blocks -> neutral (~101 us chain).
// R4: fused last-block epilogue -> VGPR 124, occ 18%, latency-bound. REGRESSED.
// R5: 1 quad/thread @12288 blocks, 16 VGPR -> 298 us total, ~88 us chain. BEST.
// R6: 2 quads/thread batched -> 302.5. Plateau ~3 TB/s across all structures.
// R7: R5 + NONTEMPORAL loads -> 280.1 us (~70 us chain, ~3.6 TB/s read).
// R8: THIS. Persistent kernel (2048 blocks = 8/CU, no re-dispatch), 6 quads/
//     thread, explicit 2-deep register double-buffer: issue next 5 nt loads
//     BEFORE computing current quad. Keeps the per-CU miss queue full through
//     compute + eliminates block retire/redispatch bubbles (duty-cycle theory).
//     All LDS/barrier reduction deferred to after the sweep.

#define HW      (512 * 512)
#define QUADS   (HW / 4)              // 65536 float4 groups per channel plane
#define NS      48                    // N*S
#define NQUAD   (NS * QUADS)          // 3,145,728 total quads
#define TPB     256
#define PBLK    2048                  // persistent: exactly 8 blocks per CU
#define STRIDE  (PBLK * TPB)          // 524,288 quads per sweep (= 8 << 16)
#define ITERS   (NQUAD / STRIDE)      // 6 sweeps per thread
#define PADV    (8 * 4 * QUADS)       // preds vf4-advance per sweep (ns += 8)
#define TADV    (8 * QUADS)           // targets vi4-advance per sweep
#define INV_N   0.125f

typedef float vf4 __attribute__((ext_vector_type(4)));
typedef int   vi4 __attribute__((ext_vector_type(4)));

__device__ __forceinline__ float nll_one(float a, float b, float c, float d, int t) {
    float m = fmaxf(fmaxf(a, b), fmaxf(c, d));
    float s = __expf(a - m) + __expf(b - m) + __expf(c - m) + __expf(d - m);
    float lse = m + __logf(s);
    float xt = (t == 0) ? a : ((t == 1) ? b : ((t == 2) ? c : d));
    return lse - xt;
}

__device__ __forceinline__ float quad_nll(vf4 x0, vf4 x1, vf4 x2, vf4 x3, vi4 t) {
    return nll_one(x0.x, x1.x, x2.x, x3.x, t.x)
         + nll_one(x0.y, x1.y, x2.y, x3.y, t.y)
         + nll_one(x0.z, x1.z, x2.z, x3.z, t.z)
         + nll_one(x0.w, x1.w, x2.w, x3.w, t.w);
}

__global__ __launch_bounds__(TPB, 8) void ce_partial(const float* __restrict__ preds,
                                                     const int* __restrict__ targets,
                                                     float* __restrict__ part) {
    const int g0  = blockIdx.x * TPB + threadIdx.x;   // quad id in sweep 0
    const int ns0 = g0 >> 16;                         // ns advances by 8 per sweep
    const int q   = g0 & (QUADS - 1);                 // q constant across sweeps

    const vf4* __restrict__ p4 = (const vf4*)preds + (size_t)ns0 * (4 * QUADS) + q;
    const vi4* __restrict__ t4 = (const vi4*)targets + (size_t)ns0 * QUADS + q;

    // ---- prologue: fill pipeline stage A (sweep 0) ----
    vf4 a0 = __builtin_nontemporal_load(p4 + 0 * QUADS);
    vf4 a1 = __builtin_nontemporal_load(p4 + 1 * QUADS);
    vf4 a2 = __builtin_nontemporal_load(p4 + 2 * QUADS);
    vf4 a3 = __builtin_nontemporal_load(p4 + 3 * QUADS);
    vi4 at = __builtin_nontemporal_load(t4);

    float lsum = 0.0f;

    #pragma unroll
    for (int i = 0; i < ITERS; i += 2) {
        // issue stage B (sweep i+1) before touching stage A's data
        const vf4* pb = p4 + (size_t)(i + 1) * PADV;
        const vi4* tb = t4 + (size_t)(i + 1) * TADV;
        vf4 b0 = __builtin_nontemporal_load(pb + 0 * QUADS);
        vf4 b1 = __builtin_nontemporal_load(pb + 1 * QUADS);
        vf4 b2 = __builtin_nontemporal_load(pb + 2 * QUADS);
        vf4 b3 = __builtin_nontemporal_load(pb + 3 * QUADS);
        vi4 bt = __builtin_nontemporal_load(tb);

        lsum += quad_nll(a0, a1, a2, a3, at);         // consume A (waits only on A)

        if (i + 2 < ITERS) {
            // refill stage A (sweep i+2) before consuming B
            const vf4* pa = p4 + (size_t)(i + 2) * PADV;
            const vi4* ta = t4 + (size_t)(i + 2) * TADV;
            a0 = __builtin_nontemporal_load(pa + 0 * QUADS);
            a1 = __builtin_nontemporal_load(pa + 1 * QUADS);
            a2 = __builtin_nontemporal_load(pa + 2 * QUADS);
            a3 = __builtin_nontemporal_load(pa + 3 * QUADS);
            at = __builtin_nontemporal_load(ta);
        }

        lsum += quad_nll(b0, b1, b2, b3, bt);         // consume B
    }

    // ---- single deferred reduction (no barriers inside the sweep loop) ----
    #pragma unroll
    for (int off = 32; off > 0; off >>= 1)
        lsum += __shfl_down(lsum, off, 64);

    __shared__ float wsum[4];
    const int lane = threadIdx.x & 63;
    const int wave = threadIdx.x >> 6;
    if (lane == 0) wsum[wave] = lsum;
    __syncthreads();
    if (threadIdx.x == 0)
        part[blockIdx.x] = (wsum[0] + wsum[1] + wsum[2] + wsum[3]) * INV_N;
}

__global__ __launch_bounds__(256) void ce_final(const float* __restrict__ part,
                                                float* __restrict__ out) {
    float lsum = 0.0f;
    #pragma unroll
    for (int i = 0; i < PBLK / 256; ++i)              // 8 iterations
        lsum += part[i * 256 + threadIdx.x];

    #pragma unroll
    for (int off = 32; off > 0; off >>= 1)
        lsum += __shfl_down(lsum, off, 64);

    __shared__ float wsum[4];
    const int lane = threadIdx.x & 63;
    const int wave = threadIdx.x >> 6;
    if (lane == 0) wsum[wave] = lsum;
    __syncthreads();
    if (threadIdx.x == 0)
        out[0] = wsum[0] + wsum[1] + wsum[2] + wsum[3];
}

extern "C" void kernel_launch(void* const* d_in, const int* in_sizes, int n_in,
                              void* d_out, int out_size, void* d_ws, size_t ws_size,
                              hipStream_t stream) {
    const float* preds   = (const float*)d_in[0];
    const int*   targets = (const int*)d_in[1];
    float*       part    = (float*)d_ws;     // PBLK floats = 8 KiB scratch
    float*       out     = (float*)d_out;

    ce_partial<<<PBLK, TPB, 0, stream>>>(preds, targets, part);
    ce_final<<<1, 256, 0, stream>>>(part, out);
}

// Round 2
// 283.688 us; speedup vs baseline: 1.3198x; 1.3198x over previous
//
#include <hip/hip_runtime.h>

// Problem: preds (N=8,S=6,C=4,H=512,W=512) fp32, targets (8,6,512,512) int32.
// out = (1/N) * sum [logsumexp_c(preds) - preds[target]]   (scalar)
//
// R1: 12288 same-address atomicAdds serialized (168 us flat).
// R2: two-stage reduction -> 310 us (harness fixed overhead ~210 us).
// R3: batched loads @1024 blocks -> neutral (~101 us chain).
// R4: fused last-block epilogue -> VGPR 124, occ 18%, latency-bound. REGRESSED.
// R5: 1 quad/thread @12288 blocks, 16 VGPR -> 298 us total, ~88 us chain. BEST.
// R6: 2 quads/thread batched -> 302.5. Plateau ~3 TB/s across all structures.
// R7: R5 + NONTEMPORAL loads -> 280.1 us (~70 us chain, ~3.9 TB/s read).
// R8: persistent 2048-block + 2-deep reg pipeline, but __launch_bounds__(256,8)
//     capped VGPR at 32 -> compiler SPILLED the pipeline (WRITE_SIZE 147.7 MB
//     of scratch, read BW 1.7 TB/s). 374 us. The pipeline never existed.
// R9: THIS. Identical structure, bound relaxed to __launch_bounds__(256) so the
//     ~55-VGPR double-buffer lives in registers (<=64 VGPR still allows 32
//     waves/CU). Clean A/B of duty-cycle theory vs per-CU miss-queue cap.

#define HW      (512 * 512)
#define QUADS   (HW / 4)              // 65536 float4 groups per channel plane
#define NS      48                    // N*S
#define NQUAD   (NS * QUADS)          // 3,145,728 total quads
#define TPB     256
#define PBLK    2048                  // persistent: exactly 8 blocks per CU
#define STRIDE  (PBLK * TPB)          // 524,288 quads per sweep (= 8 << 16)
#define ITERS   (NQUAD / STRIDE)      // 6 sweeps per thread
#define PADV    (8 * 4 * QUADS)       // preds vf4-advance per sweep (ns += 8)
#define TADV    (8 * QUADS)           // targets vi4-advance per sweep
#define INV_N   0.125f

typedef float vf4 __attribute__((ext_vector_type(4)));
typedef int   vi4 __attribute__((ext_vector_type(4)));

__device__ __forceinline__ float nll_one(float a, float b, float c, float d, int t) {
    float m = fmaxf(fmaxf(a, b), fmaxf(c, d));
    float s = __expf(a - m) + __expf(b - m) + __expf(c - m) + __expf(d - m);
    float lse = m + __logf(s);
    float xt = (t == 0) ? a : ((t == 1) ? b : ((t == 2) ? c : d));
    return lse - xt;
}

__device__ __forceinline__ float quad_nll(vf4 x0, vf4 x1, vf4 x2, vf4 x3, vi4 t) {
    return nll_one(x0.x, x1.x, x2.x, x3.x, t.x)
         + nll_one(x0.y, x1.y, x2.y, x3.y, t.y)
         + nll_one(x0.z, x1.z, x2.z, x3.z, t.z)
         + nll_one(x0.w, x1.w, x2.w, x3.w, t.w);
}

__global__ __launch_bounds__(TPB) void ce_partial(const float* __restrict__ preds,
                                                  const int* __restrict__ targets,
                                                  float* __restrict__ part) {
    const int g0  = blockIdx.x * TPB + threadIdx.x;   // quad id in sweep 0
    const int ns0 = g0 >> 16;                         // ns advances by 8 per sweep
    const int q   = g0 & (QUADS - 1);                 // q constant across sweeps

    const vf4* __restrict__ p4 = (const vf4*)preds + (size_t)ns0 * (4 * QUADS) + q;
    const vi4* __restrict__ t4 = (const vi4*)targets + (size_t)ns0 * QUADS + q;

    // ---- prologue: fill pipeline stage A (sweep 0) ----
    vf4 a0 = __builtin_nontemporal_load(p4 + 0 * QUADS);
    vf4 a1 = __builtin_nontemporal_load(p4 + 1 * QUADS);
    vf4 a2 = __builtin_nontemporal_load(p4 + 2 * QUADS);
    vf4 a3 = __builtin_nontemporal_load(p4 + 3 * QUADS);
    vi4 at = __builtin_nontemporal_load(t4);

    float lsum = 0.0f;

    #pragma unroll
    for (int i = 0; i < ITERS; i += 2) {
        // issue stage B (sweep i+1) before touching stage A's data
        const vf4* pb = p4 + (size_t)(i + 1) * PADV;
        const vi4* tb = t4 + (size_t)(i + 1) * TADV;
        vf4 b0 = __builtin_nontemporal_load(pb + 0 * QUADS);
        vf4 b1 = __builtin_nontemporal_load(pb + 1 * QUADS);
        vf4 b2 = __builtin_nontemporal_load(pb + 2 * QUADS);
        vf4 b3 = __builtin_nontemporal_load(pb + 3 * QUADS);
        vi4 bt = __builtin_nontemporal_load(tb);

        lsum += quad_nll(a0, a1, a2, a3, at);         // consume A (waits only on A)

        if (i + 2 < ITERS) {
            // refill stage A (sweep i+2) before consuming B
            const vf4* pa = p4 + (size_t)(i + 2) * PADV;
            const vi4* ta = t4 + (size_t)(i + 2) * TADV;
            a0 = __builtin_nontemporal_load(pa + 0 * QUADS);
            a1 = __builtin_nontemporal_load(pa + 1 * QUADS);
            a2 = __builtin_nontemporal_load(pa + 2 * QUADS);
            a3 = __builtin_nontemporal_load(pa + 3 * QUADS);
            at = __builtin_nontemporal_load(ta);
        }

        lsum += quad_nll(b0, b1, b2, b3, bt);         // consume B
    }

    // ---- single deferred reduction (no barriers inside the sweep loop) ----
    #pragma unroll
    for (int off = 32; off > 0; off >>= 1)
        lsum += __shfl_down(lsum, off, 64);

    __shared__ float wsum[4];
    const int lane = threadIdx.x & 63;
    const int wave = threadIdx.x >> 6;
    if (lane == 0) wsum[wave] = lsum;
    __syncthreads();
    if (threadIdx.x == 0)
        part[blockIdx.x] = (wsum[0] + wsum[1] + wsum[2] + wsum[3]) * INV_N;
}

__global__ __launch_bounds__(256) void ce_final(const float* __restrict__ part,
                                                float* __restrict__ out) {
    float lsum = 0.0f;
    #pragma unroll
    for (int i = 0; i < PBLK / 256; ++i)              // 8 iterations
        lsum += part[i * 256 + threadIdx.x];

    #pragma unroll
    for (int off = 32; off > 0; off >>= 1)
        lsum += __shfl_down(lsum, off, 64);

    __shared__ float wsum[4];
    const int lane = threadIdx.x & 63;
    const int wave = threadIdx.x >> 6;
    if (lane == 0) wsum[wave] = lsum;
    __syncthreads();
    if (threadIdx.x == 0)
        out[0] = wsum[0] + wsum[1] + wsum[2] + wsum[3];
}

extern "C" void kernel_launch(void* const* d_in, const int* in_sizes, int n_in,
                              void* d_out, int out_size, void* d_ws, size_t ws_size,
                              hipStream_t stream) {
    const float* preds   = (const float*)d_in[0];
    const int*   targets = (const int*)d_in[1];
    float*       part    = (float*)d_ws;     // PBLK floats = 8 KiB scratch
    float*       out     = (float*)d_out;

    ce_partial<<<PBLK, TPB, 0, stream>>>(preds, targets, part);
    ce_final<<<1, 256, 0, stream>>>(part, out);
}